// Round 9
// baseline (499.276 us; speedup 1.0000x reference)
//
#include <hip/hip_runtime.h>

#define N_NODES 100000
#define N_EDGES 1600000
#define N_GRAPHS 512
#define HID 64
#define NUM_CLASSES 100
#define ID_OFFSET 1500
#define BN_EPS 1e-5f
#define CAP 64
#define NBKT 256
#define BSHIFT 9
#define NUSED ((N_NODES + 511) >> 9)   // 196 buckets of 512 nodes
#define BCAP 10240                      // per-bucket record capacity
#define CBLK 98
#define CHUNK 16384
#define WPBLK 5                         // wprep blocks inside prep_kernel
#define EMBBLK ((N_NODES * 32 + 1023) / 1024)   // 3125
#define DUMMY_ROW 100000                // zeroed row in x-buffer slack, pad target
#define SREP 16                         // stats atomic replicas (contention fix)
#define SSTRIDE 384                     // floats per stats replica

typedef __attribute__((ext_vector_type(8))) short short8;
typedef __attribute__((ext_vector_type(4))) float floatx4;

__device__ __forceinline__ float b2f(unsigned short u) {
    return __builtin_bit_cast(float, ((unsigned)u) << 16);
}
__device__ __forceinline__ unsigned short f2b(float f) {   // RNE
    unsigned x = __builtin_bit_cast(unsigned, f);
    x += 0x7FFFu + ((x >> 16) & 1u);
    return (unsigned short)(x >> 16);
}

// async global->LDS, 16B per lane; LDS dest = uniform base + lane*16 (HW rule)
__device__ __forceinline__ void gload_lds16(const void* g, void* l) {
    __builtin_amdgcn_global_load_lds(
        (const __attribute__((address_space(1))) void*)g,
        (__attribute__((address_space(3))) void*)l, 16, 0, 0);
}

// swizzled granule layout: 16-row tiles, 8 granules(16B)/row, granule slot = (row&15)^q
#define XSH(row, qq) ((((((row) >> 4) << 7) + ((qq) << 4) + (((row) & 15) ^ (qq))) * 8))

// ---------------- fused prep: binning + wprep + embed + dummy-row zero ----------------

__global__ __launch_bounds__(1024) void prep_kernel(const int* __restrict__ src,
                                                    const int* __restrict__ dst,
                                                    int* __restrict__ cursor,
                                                    int* __restrict__ rec,
                                                    const float* __restrict__ Ws,
                                                    unsigned short* __restrict__ whi,
                                                    unsigned short* __restrict__ wlo,
                                                    const int* __restrict__ node_ids,
                                                    const int* __restrict__ gid,
                                                    const float* __restrict__ emb,
                                                    unsigned short* __restrict__ h,
                                                    unsigned short* __restrict__ xin,
                                                    int* __restrict__ gs,
                                                    int* __restrict__ ge) {
    __shared__ int hist[NBKT];
    __shared__ int base_s[NBKT];
    int t = threadIdx.x;
    int blk = blockIdx.x;

    if (blk < CBLK) {
        // ---- dummy-row zeroing piggybacked on block 0 (replaces 2 memset launches)
        if (blk == 0 && t < 32) {
            ((unsigned*)(h + (size_t)DUMMY_ROW * 64))[t] = 0u;
            ((unsigned*)(xin + (size_t)DUMMY_ROW * 64))[t] = 0u;
        }
        // ---- edge binning (one pass) ----
        if (t < NBKT) hist[t] = 0;
        __syncthreads();
        int cb = blk * CHUNK;
        int d_[16], s_[16];
#pragma unroll
        for (int k = 0; k < 16; ++k) {
            int i = cb + k * 1024 + t;
            d_[k] = (i < N_EDGES) ? dst[i] : -1;
            s_[k] = (i < N_EDGES) ? src[i] : 0;
            if (d_[k] >= 0) atomicAdd(&hist[((unsigned)d_[k] >> BSHIFT) & (NBKT - 1)], 1);
        }
        __syncthreads();
        if (t < NBKT) base_s[t] = (hist[t] > 0) ? atomicAdd(&cursor[t], hist[t]) : 0;
        __syncthreads();
        if (t < NBKT) hist[t] = 0;
        __syncthreads();
#pragma unroll
        for (int k = 0; k < 16; ++k) {
            if (d_[k] >= 0) {
                unsigned d = (unsigned)d_[k];
                int b = (d >> BSHIFT) & (NBKT - 1);
                int p = atomicAdd(&hist[b], 1);
                int g = base_s[b] + p;
                if ((unsigned)g < BCAP)
                    rec[b * BCAP + g] = ((int)(d & 511) << 17) | (s_[k] & 0x1FFFF);
            }
        }
    } else if (blk < CBLK + WPBLK) {
        // ---- W pre-convert + pre-swizzle, hi/lo split ----
        int G = (blk - CBLK) * 1024 + t;
        if (G < 3 * 1536) {
            int l = G / 1536, Gp = G % 1536;
            int mm = Gp >> 9, rem = Gp & 511;
            int kq = rem >> 6, n = rem & 63;
            const float* Wp = Ws + l * 12288 + mm * 4096 + (kq * 8) * 64 + n;
            unsigned short uh[8], ul[8];
#pragma unroll
            for (int j = 0; j < 8; ++j) {
                float w = Wp[j * 64];
                unsigned short hi = f2b(w);
                uh[j] = hi;
                ul[j] = f2b(w - b2f(hi));
            }
            size_t off = (size_t)l * 12288 + (mm << 12) + XSH(n, kq);
            *(short8*)&whi[off] = *(short8*)uh;
            *(short8*)&wlo[off] = *(short8*)ul;
        }
    } else {
        // ---- embedding gather (bf16) + sorted-graph span boundaries ----
        int idx = (blk - CBLK - WPBLK) * 1024 + t;
        if (idx < N_NODES * 32) {
            int n = idx >> 5, cp = idx & 31;
            const float2 e = *(const float2*)(emb + (((size_t)(node_ids[n] + ID_OFFSET)) << 6) + cp * 2);
            unsigned v = (unsigned)f2b(e.x) | ((unsigned)f2b(e.y) << 16);
            ((unsigned*)h)[n * 32 + cp] = v;
            if (cp == 0) {
                int g = gid[n] & (N_GRAPHS - 1);
                if (n == 0 || (gid[n - 1] & (N_GRAPHS - 1)) != g) gs[g] = n;
                if (n == N_NODES - 1 || (gid[n + 1] & (N_GRAPHS - 1)) != g) ge[g] = n + 1;
            }
        }
    }
}

// ---------------- per-bucket CSR fill (pads rows to >=32, then multiple of 16) ----------------

__global__ __launch_bounds__(1024) void fill_kernel(const int* __restrict__ rec,
                                                    const int* __restrict__ cursor,
                                                    int* __restrict__ cnt,
                                                    int* __restrict__ srcs) {
    __shared__ int lcnt[512];
    int t = threadIdx.x;
    int b = blockIdx.x;            // 0..NUSED-1
    if (t < 512) lcnt[t] = 0;
    __syncthreads();
    int nb = cursor[b];
    if (nb < 0) nb = 0;
    if (nb > BCAP) nb = BCAP;
    const int* seg = rec + b * BCAP;
    for (int i = t; i < nb; i += 1024) {
        unsigned r = (unsigned)seg[i];
        int dl = (int)((r >> 17) & 511);
        int s = (int)(r & 0x1FFFF);
        int node = (b << BSHIFT) + dl;
        int p = atomicAdd(&lcnt[dl], 1);
        if (p < CAP && node < N_NODES) srcs[(node << 6) + p] = s;
    }
    __syncthreads();
    if (t < 512) {
        int node = (b << BSHIFT) + t;
        if (node < N_NODES) {
            int deg = lcnt[t];
            cnt[node] = deg;
            int degc = deg > CAP ? CAP : deg;
            int degp = (degc + 15) & ~15;
            if (degp < 32) degp = 32;
            // pad with dummy index -> zeroed row; lets gather run unmasked 32-edge bursts
            for (int p = degc; p < degp; ++p) srcs[(node << 6) + p] = DUMMY_ROW;
        }
    }
}

// ---------------- FUSED GIN layer v7: global_load_lds gather, zero landing VGPRs ----------------
// R8 autopsy: occupancy 59% (theory confirmed) but VGPR 40 -> compiler chunk-serialized
// the register burst; per-wave BW 0.24 GB/s. Structural conflict: wide burst needs 64+
// VGPRs, 32 waves/CU needs <=64. v7 escapes via global_load_lds: 4 dwordx4 instrs/wave
// stream 32 edge-rows (4 KB) to LDS with NO landing registers (per-lane global addr,
// lane-linear LDS dest). 1024-thr blocks, 16 waves, 1 node/wave; LDS ~70 KB -> 2
// blocks/CU = 32 waves/CU, grid 6250 = 24 blocks/CU supply -> constant refill.
// __syncthreads() provides the vmcnt(0) drain exactly where consumption starts.

__global__ __launch_bounds__(1024, 8) void fused_kernel(const unsigned short* __restrict__ x,
                                                        unsigned short* __restrict__ xo,
                                                        const int* __restrict__ cnt,
                                                        const int* __restrict__ srcs,
                                                        const float* __restrict__ eps, int l,
                                                        float* __restrict__ stats,
                                                        const float* __restrict__ gamma,
                                                        const float* __restrict__ beta,
                                                        const unsigned short* __restrict__ whi,
                                                        const unsigned short* __restrict__ wlo,
                                                        const float* __restrict__ bs,
                                                        const int* __restrict__ graph_ids,
                                                        float* __restrict__ pooled, int last) {
    __shared__ __align__(16) unsigned char land[16 * 4096];   // 64 KB gather landing
    __shared__ __align__(16) unsigned short xs[2 * 16 * 64];  // 4 KB double buffer
    __shared__ float bnab[128];                               // a[64], b[64]
    __shared__ int garr[16];
    int t = threadIdx.x;
    int lane = t & 63, w = t >> 6;
    int half = lane >> 5, cl = lane & 31;
    int nodebase = blockIdx.x * 16;
    int node = __builtin_amdgcn_readfirstlane(nodebase + (t >> 6));
    const unsigned* __restrict__ xu = (const unsigned*)x;

    if (t < 16) garr[t] = graph_ids[nodebase + t] & (N_GRAPHS - 1);

    float scale = 1.0f + eps[l];

    // ---- BN coeffs for layer l-1: ONCE per block (t<64), replica-summed into LDS
    if (t < 64) {
        float a = 1.0f, b = 0.0f;
        if (l > 0) {
            int lp = l - 1;
            float S = 0.f, Q = 0.f;
#pragma unroll
            for (int rp = 0; rp < SREP; ++rp) {
                S += stats[rp * SSTRIDE + lp * 128 + t];
                Q += stats[rp * SSTRIDE + lp * 128 + 64 + t];
            }
            float mean = S * (1.0f / N_NODES);
            float var = Q * (1.0f / N_NODES) - mean * mean;
            float r = rsqrtf(var + BN_EPS);
            a = gamma[lp * 64 + t] * r;
            b = beta[lp * 64 + t] - mean * a;
        }
        bnab[t] = a;
        bnab[64 + t] = b;
    }

    // ---- gather issue: this wave's node, 32 padded edges -> 4 async dwordx4 loads
    int d = cnt[node];
    int dc = d < 0 ? 0 : (d > CAP ? CAP : d);
    int dp = (dc + 15) & ~15;
    if (dp < 32) dp = 32;
    const int* row = srcs + ((size_t)node << 6);
    int ridx = row[lane & 31];                       // 32 indices, one coalesced load
    unsigned char* ldst = land + w * 4096;
#pragma unroll
    for (int j = 0; j < 4; ++j) {
        int e = __shfl(ridx, 8 * j + (lane >> 3)) & 0x1FFFF;   // edge for this lane's 16B chunk
        const unsigned short* gp = x + ((size_t)e << 6) + (lane & 7) * 8;
        gload_lds16(gp, ldst + j * 1024);
    }
    unsigned us = xu[(size_t)node * 32 + cl];        // self row (same burst)

    float A0 = 0.f, A1 = 0.f, B0 = 0.f, B1 = 0.f;

    // ---- remainder (deg>32, ~1e-4 of nodes): register path, wave-uniform branch
    for (int c = 32; c < dp; c += 16) {
        unsigned uc[8];
#pragma unroll
        for (int k = 0; k < 8; ++k) {
            int ia = row[c + 2 * k] & 0x1FFFF;
            int ib = row[c + 2 * k + 1] & 0x1FFFF;
            int idx = half ? ib : ia;
            uc[k] = xu[(size_t)idx * 32 + cl];
        }
#pragma unroll
        for (int k = 0; k < 8; ++k) {
            float lo = b2f((unsigned short)(uc[k] & 0xFFFF));
            float hi = b2f((unsigned short)(uc[k] >> 16));
            if (k & 1) { B0 += lo; B1 += hi; }
            else       { A0 += lo; A1 += hi; }
        }
    }

    __syncthreads();   // drains own vmcnt (land ready); bnab/garr visible

    // ---- consume from LDS: half h handles edges 8j+4h+k (k=0..3), channel cl
    {
        const unsigned* lp = (const unsigned*)(land + w * 4096);
#pragma unroll
        for (int j = 0; j < 4; ++j)
#pragma unroll
            for (int k = 0; k < 4; ++k) {
                unsigned u = lp[(8 * j + 4 * half + k) * 32 + cl];
                float lo = b2f((unsigned short)(u & 0xFFFF));
                float hi = b2f((unsigned short)(u >> 16));
                if (k & 1) { B0 += lo; B1 += hi; }
                else       { A0 += lo; A1 += hi; }
            }
    }

    // ---- reduce halves + BN affine + write bf16 into xs buf0 (own row)
    {
        float S0 = A0 + B0;
        float S1 = A1 + B1;
        S0 += __shfl_xor(S0, 32);
        S1 += __shfl_xor(S1, 32);
        if (half == 0) {
            float a0f = bnab[2 * cl], a1f = bnab[2 * cl + 1];
            float b0f = bnab[64 + 2 * cl], b1f = bnab[64 + 2 * cl + 1];
            float selflo = b2f((unsigned short)(us & 0xFFFF));
            float selfhi = b2f((unsigned short)(us >> 16));
            float db = scale + (float)dc;
            float v0 = fmaf(a0f, fmaf(scale, selflo, S0), db * b0f);
            float v1 = fmaf(a1f, fmaf(scale, selfhi, S1), db * b1f);
            int col = 2 * cl;
            *(unsigned*)&xs[XSH(w, col >> 3) + (col & 7)] =
                (unsigned)f2b(v0) | ((unsigned)f2b(v1) << 16);
        }
    }
    __syncthreads();   // xs buf0 complete across all 16 waves

    // ---- MFMA MLP: waves 0-3 compute the 16x64 tile (q==w row-keep), others sync
    int m = lane & 15, q = lane >> 4;
    const float* bb = bs + l * 3 * 64;
    const unsigned short* whil = whi + (size_t)l * 12288;
    const unsigned short* wlol = wlo + (size_t)l * 12288;
    for (int mm = 0; mm < 3; ++mm) {
        if (w < 4) {
            unsigned short* xr = xs + (mm & 1) * 1024;          // read buffer
            unsigned short* xw = xs + ((mm & 1) ^ 1) * 1024;    // write buffer
            short8 bl[2][4];
#pragma unroll
            for (int kc = 0; kc < 2; ++kc)
#pragma unroll
                for (int tj = 0; tj < 4; ++tj)
                    bl[kc][tj] = *(const short8*)&wlol[(mm << 12) + XSH(tj * 16 + m, kc * 4 + q)];
            short8 a[2];
#pragma unroll
            for (int kc = 0; kc < 2; ++kc)
                a[kc] = *(const short8*)&xr[XSH(m, kc * 4 + q)];

            floatx4 acc[4];
#pragma unroll
            for (int tj = 0; tj < 4; ++tj) {
                float bv = bb[mm * 64 + tj * 16 + m];
                acc[tj] = (floatx4){bv, bv, bv, bv};
            }
#pragma unroll
            for (int kc = 0; kc < 2; ++kc) {
                short8 bh[4];
#pragma unroll
                for (int tj = 0; tj < 4; ++tj)
                    bh[tj] = *(const short8*)&whil[(mm << 12) + XSH(tj * 16 + m, kc * 4 + q)];
#pragma unroll
                for (int tj = 0; tj < 4; ++tj)
                    acc[tj] = __builtin_amdgcn_mfma_f32_16x16x32_bf16(a[kc], bh[tj], acc[tj], 0, 0, 0);
            }
#pragma unroll
            for (int kc = 0; kc < 2; ++kc)
#pragma unroll
                for (int tj = 0; tj < 4; ++tj)
                    acc[tj] = __builtin_amdgcn_mfma_f32_16x16x32_bf16(a[kc], bl[kc][tj], acc[tj], 0, 0, 0);
#pragma unroll
            for (int tj = 0; tj < 4; ++tj) {
                int col = tj * 16 + m;
                if (q == w) {
#pragma unroll
                    for (int r = 0; r < 4; ++r) {
                        int rowi = q * 4 + r;
                        float v = acc[tj][r];
                        xw[XSH(rowi, col >> 3) + (col & 7)] = f2b(v > 0.f ? v : 0.f);
                    }
                }
            }
        }
        __syncthreads();
    }

    unsigned short* xf = xs + 1024;   // mm=2 wrote buf1

    // ---- writeback (own row) + pool/stats via block-wide LDS reduce (reuse land)
    float v;
    {
        int col = lane;
        v = b2f(xf[XSH(w, col >> 3) + (col & 7)]);
    }
    if (!last && half == 0) {
        int col = 2 * cl;
        unsigned val = *(const unsigned*)&xf[XSH(w, col >> 3) + (col & 7)];
        ((unsigned*)xo)[(size_t)node * 32 + cl] = val;
    }
    float* ssum = (float*)land;              // reuse: landing area is dead
    float* sqq = (float*)(land + 4096);
    ssum[t] = v;
    sqq[t] = v * v;
    __syncthreads();
    if (t < 64) {
        float S = 0.f, Q = 0.f, acc2 = 0.f;
        int cur = -1;
#pragma unroll
        for (int k = 0; k < 16; ++k) {
            float vv = ssum[k * 64 + t];
            S += vv;
            Q += sqq[k * 64 + t];
            int g = garr[k];
            if (g != cur) {
                if (cur >= 0) atomicAdd(&pooled[cur * 192 + l * 64 + t], acc2);
                acc2 = 0.f;
                cur = g;
            }
            acc2 += vv;
        }
        if (cur >= 0) atomicAdd(&pooled[cur * 192 + l * 64 + t], acc2);
        float* sp = stats + (blockIdx.x & (SREP - 1)) * SSTRIDE + l * 128;
        atomicAdd(&sp[t], S);
        atomicAdd(&sp[64 + t], Q);
    }
}

// ---------------- final classifier (replica-summed stats) ----------------

__global__ __launch_bounds__(256) void out_kernel(const float* __restrict__ pooled,
                                                  const float* __restrict__ stats,
                                                  const float* __restrict__ gamma,
                                                  const float* __restrict__ beta,
                                                  const int* __restrict__ gs,
                                                  const int* __restrict__ ge,
                                                  const float* __restrict__ Wo,
                                                  const float* __restrict__ bo,
                                                  float* __restrict__ out) {
    __shared__ float sab[384];
    int t = threadIdx.x;
    if (t < 192) {
        int l2 = t / 64, c = t & 63;
        float S = 0.f, Q = 0.f;
#pragma unroll
        for (int rp = 0; rp < SREP; ++rp) {
            S += stats[rp * SSTRIDE + l2 * 128 + c];
            Q += stats[rp * SSTRIDE + l2 * 128 + 64 + c];
        }
        float mean = S * (1.0f / N_NODES);
        float var = Q * (1.0f / N_NODES) - mean * mean;
        float rstd = rsqrtf(var + BN_EPS);
        float a = gamma[l2 * 64 + c] * rstd;
        sab[l2 * 128 + c] = a;
        sab[l2 * 128 + 64 + c] = beta[l2 * 64 + c] - mean * a;
    }
    __syncthreads();
    int idx = blockIdx.x * blockDim.x + t;
    if (idx < N_GRAPHS * NUM_CLASSES) {
        int g = idx / NUM_CLASSES, k = idx % NUM_CLASSES;
        float cg = (float)(ge[g] - gs[g]);
        float acc = bo[k];
        for (int l2 = 0; l2 < 3; ++l2)
            for (int c = 0; c < 64; ++c) {
                float gf = fmaf(sab[l2 * 128 + c], pooled[g * 192 + l2 * 64 + c],
                                sab[l2 * 128 + 64 + c] * cg);
                acc = fmaf(gf, Wo[(l2 * 64 + c) * NUM_CLASSES + k], acc);
            }
        out[idx] = acc;
    }
}

extern "C" void kernel_launch(void* const* d_in, const int* in_sizes, int n_in,
                              void* d_out, int out_size, void* d_ws, size_t ws_size,
                              hipStream_t stream) {
    const int*   node_ids  = (const int*)d_in[0];
    const int*   edge_src  = (const int*)d_in[1];
    const int*   edge_dst  = (const int*)d_in[2];
    const int*   graph_ids = (const int*)d_in[3];
    const float* emb       = (const float*)d_in[4];
    const float* Ws        = (const float*)d_in[5];
    const float* bs        = (const float*)d_in[6];
    const float* gamma     = (const float*)d_in[7];
    const float* beta      = (const float*)d_in[8];
    const float* eps       = (const float*)d_in[9];
    const float* W_out     = (const float*)d_in[10];
    const float* b_out     = (const float*)d_in[11];
    float* out = (float*)d_out;

    // workspace
    unsigned short* h    = (unsigned short*)d_ws;         // 6,400,000 sh (+8192 slack)
    unsigned short* xin  = h + 6400000 + 8192;            // 6,400,000 sh (+8192 slack)
    unsigned short* whi  = xin + 6400000 + 8192;          // 36,864 sh
    unsigned short* wlo  = whi + 36864;                   // 36,864 sh
    int*   srcs   = (int*)(wlo + 36864);                  // 6,400,000 i (padded CSR)
    int*   rec    = srcs + 6400000;                       // NUSED*BCAP i
    float* pooled = (float*)(rec + NUSED * BCAP);         // 98,304 f
    float* stats  = pooled + 98304;                       // SREP*SSTRIDE = 6,144 f
    int*   cnt    = (int*)(stats + SREP * SSTRIDE);       // 100,000 i
    int*   gs     = cnt + 100000;                         // 512 i
    int*   ge     = gs + 512;                             // 512 i
    int*   cursor = ge + 512;                             // 256 i (bucket totals)

    hipMemsetAsync(pooled, 0,
                   (size_t)(98304 + SREP * SSTRIDE + 100000 + 512 + 512 + 256) * 4, stream);

    prep_kernel<<<CBLK + WPBLK + EMBBLK, 1024, 0, stream>>>(
        edge_src, edge_dst, cursor, rec, Ws, whi, wlo,
        node_ids, graph_ids, emb, h, xin, gs, ge);
    fill_kernel<<<NUSED, 1024, 0, stream>>>(rec, cursor, cnt, srcs);

    const int FUSE_BLK = N_NODES / 16;   // 6250 blocks x 16 waves = 100000 waves
    for (int l = 0; l < 3; ++l) {
        const unsigned short* X = (l % 2 == 0) ? h : xin;   // gather source
        unsigned short* A = (l % 2 == 0) ? xin : h;         // this-layer output
        fused_kernel<<<FUSE_BLK, 1024, 0, stream>>>(
            X, A, cnt, srcs, eps, l, stats, gamma, beta,
            whi, wlo, bs, graph_ids, pooled, l == 2);
    }

    out_kernel<<<(N_GRAPHS * NUM_CLASSES + 255) / 256, 256, 0, stream>>>(
        pooled, stats, gamma, beta, gs, ge, W_out, b_out, out);
}

// Round 10
// 299.733 us; speedup vs baseline: 1.6657x; 1.6657x over previous
//
#include <hip/hip_runtime.h>

#define N_NODES 100000
#define N_EDGES 1600000
#define N_GRAPHS 512
#define HID 64
#define NUM_CLASSES 100
#define ID_OFFSET 1500
#define BN_EPS 1e-5f
#define CAP 64
#define NBKT 256
#define BSHIFT 9
#define NUSED ((N_NODES + 511) >> 9)   // 196 buckets of 512 nodes
#define BCAP 10240                      // per-bucket record capacity
#define CBLK 98
#define CHUNK 16384
#define WPBLK 5                         // wprep blocks inside prep_kernel
#define EMBBLK ((N_NODES * 32 + 1023) / 1024)   // 3125
#define DUMMY_ROW 100000                // zeroed row in x-buffer slack, pad target
#define SREP 8                          // stats atomic replicas
#define SSTRIDE 384                     // floats per stats replica

typedef __attribute__((ext_vector_type(8))) short short8;
typedef __attribute__((ext_vector_type(4))) float floatx4;

__device__ __forceinline__ float b2f(unsigned short u) {
    return __builtin_bit_cast(float, ((unsigned)u) << 16);
}
__device__ __forceinline__ unsigned short f2b(float f) {   // RNE
    unsigned x = __builtin_bit_cast(unsigned, f);
    x += 0x7FFFu + ((x >> 16) & 1u);
    return (unsigned short)(x >> 16);
}

// swizzled granule layout: 16-row tiles, 8 granules(16B)/row, granule slot = (row&15)^q
#define XSH(row, qq) ((((((row) >> 4) << 7) + ((qq) << 4) + (((row) & 15) ^ (qq))) * 8))

// ---------------- fused prep: binning + wprep + embed + dummy-row zero ----------------

__global__ __launch_bounds__(1024) void prep_kernel(const int* __restrict__ src,
                                                    const int* __restrict__ dst,
                                                    int* __restrict__ cursor,
                                                    int* __restrict__ rec,
                                                    const float* __restrict__ Ws,
                                                    unsigned short* __restrict__ whi,
                                                    unsigned short* __restrict__ wlo,
                                                    const int* __restrict__ node_ids,
                                                    const int* __restrict__ gid,
                                                    const float* __restrict__ emb,
                                                    unsigned short* __restrict__ h,
                                                    unsigned short* __restrict__ xin,
                                                    int* __restrict__ gs,
                                                    int* __restrict__ ge) {
    __shared__ int hist[NBKT];
    __shared__ int base_s[NBKT];
    int t = threadIdx.x;
    int blk = blockIdx.x;

    if (blk < CBLK) {
        // ---- dummy-row zeroing piggybacked on block 0 (replaces 2 memset launches)
        if (blk == 0 && t < 32) {
            ((unsigned*)(h + (size_t)DUMMY_ROW * 64))[t] = 0u;
            ((unsigned*)(xin + (size_t)DUMMY_ROW * 64))[t] = 0u;
        }
        // ---- edge binning (one pass) ----
        if (t < NBKT) hist[t] = 0;
        __syncthreads();
        int cb = blk * CHUNK;
        int d_[16], s_[16];
#pragma unroll
        for (int k = 0; k < 16; ++k) {
            int i = cb + k * 1024 + t;
            d_[k] = (i < N_EDGES) ? dst[i] : -1;
            s_[k] = (i < N_EDGES) ? src[i] : 0;
            if (d_[k] >= 0) atomicAdd(&hist[((unsigned)d_[k] >> BSHIFT) & (NBKT - 1)], 1);
        }
        __syncthreads();
        if (t < NBKT) base_s[t] = (hist[t] > 0) ? atomicAdd(&cursor[t], hist[t]) : 0;
        __syncthreads();
        if (t < NBKT) hist[t] = 0;
        __syncthreads();
#pragma unroll
        for (int k = 0; k < 16; ++k) {
            if (d_[k] >= 0) {
                unsigned d = (unsigned)d_[k];
                int b = (d >> BSHIFT) & (NBKT - 1);
                int p = atomicAdd(&hist[b], 1);
                int g = base_s[b] + p;
                if ((unsigned)g < BCAP)
                    rec[b * BCAP + g] = ((int)(d & 511) << 17) | (s_[k] & 0x1FFFF);
            }
        }
    } else if (blk < CBLK + WPBLK) {
        // ---- W pre-convert + pre-swizzle, hi/lo split ----
        int G = (blk - CBLK) * 1024 + t;
        if (G < 3 * 1536) {
            int l = G / 1536, Gp = G % 1536;
            int mm = Gp >> 9, rem = Gp & 511;
            int kq = rem >> 6, n = rem & 63;
            const float* Wp = Ws + l * 12288 + mm * 4096 + (kq * 8) * 64 + n;
            unsigned short uh[8], ul[8];
#pragma unroll
            for (int j = 0; j < 8; ++j) {
                float w = Wp[j * 64];
                unsigned short hi = f2b(w);
                uh[j] = hi;
                ul[j] = f2b(w - b2f(hi));
            }
            size_t off = (size_t)l * 12288 + (mm << 12) + XSH(n, kq);
            *(short8*)&whi[off] = *(short8*)uh;
            *(short8*)&wlo[off] = *(short8*)ul;
        }
    } else {
        // ---- embedding gather (bf16) + sorted-graph span boundaries ----
        int idx = (blk - CBLK - WPBLK) * 1024 + t;
        if (idx < N_NODES * 32) {
            int n = idx >> 5, cp = idx & 31;
            const float2 e = *(const float2*)(emb + (((size_t)(node_ids[n] + ID_OFFSET)) << 6) + cp * 2);
            unsigned v = (unsigned)f2b(e.x) | ((unsigned)f2b(e.y) << 16);
            ((unsigned*)h)[n * 32 + cp] = v;
            if (cp == 0) {
                int g = gid[n] & (N_GRAPHS - 1);
                if (n == 0 || (gid[n - 1] & (N_GRAPHS - 1)) != g) gs[g] = n;
                if (n == N_NODES - 1 || (gid[n + 1] & (N_GRAPHS - 1)) != g) ge[g] = n + 1;
            }
        }
    }
}

// ---------------- per-bucket CSR fill (pads rows to multiple of 16, min 16) ----------------
// R10: the pad loop is now block-parallel (predicated over all 64 slots x 512 nodes)
// instead of a serial <=15-store loop in 512 threads.

__global__ __launch_bounds__(1024) void fill_kernel(const int* __restrict__ rec,
                                                    const int* __restrict__ cursor,
                                                    int* __restrict__ cnt,
                                                    int* __restrict__ srcs) {
    __shared__ int lcnt[512];
    int t = threadIdx.x;
    int b = blockIdx.x;            // 0..NUSED-1
    if (t < 512) lcnt[t] = 0;
    __syncthreads();
    int nb = cursor[b];
    if (nb < 0) nb = 0;
    if (nb > BCAP) nb = BCAP;
    const int* seg = rec + b * BCAP;
    for (int i = t; i < nb; i += 1024) {
        unsigned r = (unsigned)seg[i];
        int dl = (int)((r >> 17) & 511);
        int s = (int)(r & 0x1FFFF);
        int node = (b << BSHIFT) + dl;
        int p = atomicAdd(&lcnt[dl], 1);
        if (p < CAP && node < N_NODES) srcs[(node << 6) + p] = s;
    }
    __syncthreads();
    if (t < 512) {
        int node = (b << BSHIFT) + t;
        if (node < N_NODES) cnt[node] = lcnt[t];
    }
    __syncthreads();
    // block-parallel padding: slot p of node nl gets DUMMY if degc <= p < degp
    for (int i = t; i < 512 * 64; i += 1024) {
        int nl = i >> 6, p = i & 63;
        int node = (b << BSHIFT) + nl;
        if (node < N_NODES) {
            int deg = lcnt[nl];
            int degc = deg > CAP ? CAP : deg;
            int degp = (degc + 15) & ~15;
            if (degp < 16) degp = 16;
            if (p >= degc && p < degp) srcs[(node << 6) + p] = DUMMY_ROW;
        }
    }
}

// ---------------- GIN aggregation (R1 version, proven 2.15 TB/s; SREP-summed BN) ----------------

__global__ __launch_bounds__(256) void agg_kernel(const unsigned short* __restrict__ x,
                                                  const int* __restrict__ cnt,
                                                  const int* __restrict__ srcs,
                                                  const float* __restrict__ eps, int l,
                                                  const float* __restrict__ stats,
                                                  const float* __restrict__ gamma,
                                                  const float* __restrict__ beta,
                                                  unsigned short* __restrict__ out) {
    int nb = __builtin_amdgcn_readfirstlane(((blockIdx.x << 2) + (threadIdx.x >> 6)) << 2);
    int lane = threadIdx.x & 63;
    int half = lane >> 5;
    int cl = lane & 31;
    const unsigned* __restrict__ xu = (const unsigned*)x;

    // ---- BN coefficients for layer l-1 (replica-summed), prefetched early
    float scale = 1.0f + eps[l];
    float a0f = 1.0f, a1f = 1.0f, b0f = 0.0f, b1f = 0.0f;
    if (l > 0) {
        int lp = l - 1;
        float sm0 = 0.f, sm1 = 0.f, sq0 = 0.f, sq1 = 0.f;
#pragma unroll
        for (int rp = 0; rp < SREP; ++rp) {
            const float* sp = stats + rp * SSTRIDE + lp * 128;
            float2 a_ = *(const float2*)&sp[2 * cl];
            float2 b_ = *(const float2*)&sp[64 + 2 * cl];
            sm0 += a_.x; sm1 += a_.y;
            sq0 += b_.x; sq1 += b_.y;
        }
        float2 gm = *(const float2*)&gamma[lp * 64 + 2 * cl];
        float2 bt = *(const float2*)&beta[lp * 64 + 2 * cl];
        float mean0 = sm0 * (1.0f / N_NODES);
        float var0 = sq0 * (1.0f / N_NODES) - mean0 * mean0;
        float r0 = rsqrtf(var0 + BN_EPS);
        a0f = gm.x * r0;
        b0f = bt.x - mean0 * a0f;
        float mean1 = sm1 * (1.0f / N_NODES);
        float var1 = sq1 * (1.0f / N_NODES) - mean1 * mean1;
        float r1 = rsqrtf(var1 + BN_EPS);
        a1f = gm.y * r1;
        b1f = bt.y - mean1 * a1f;
    }

    // ---- degrees + row pointers for 4 consecutive nodes (scalar loads)
    int deg[4], degp[4];
    const int* row[4];
#pragma unroll
    for (int n = 0; n < 4; ++n) {
        int d = cnt[nb + n];
        int dc = d < 0 ? 0 : (d > CAP ? CAP : d);
        deg[n] = dc;
        int dp = (dc + 15) & ~15;
        degp[n] = dp < 16 ? 16 : dp;
        row[n] = srcs + ((size_t)(nb + n) << 6);
    }
    int cmax = degp[0];
    cmax = degp[1] > cmax ? degp[1] : cmax;
    cmax = degp[2] > cmax ? degp[2] : cmax;
    cmax = degp[3] > cmax ? degp[3] : cmax;

    // ---- self rows (issued alongside the gather burst)
    unsigned us[4];
#pragma unroll
    for (int n = 0; n < 4; ++n) us[n] = xu[(size_t)(nb + n) * 32 + cl];

    float A0[4] = {0.f, 0.f, 0.f, 0.f}, A1[4] = {0.f, 0.f, 0.f, 0.f};
    float B0[4] = {0.f, 0.f, 0.f, 0.f}, B1[4] = {0.f, 0.f, 0.f, 0.f};

    // ---- chunk 0: unconditional for all 4 nodes (rows padded to >=16), 32 loads in flight
    {
        unsigned uv[4][8];
#pragma unroll
        for (int n = 0; n < 4; ++n)
#pragma unroll
            for (int k = 0; k < 8; ++k) {
                int ia = row[n][2 * k] & 0x1FFFF;
                int ib = row[n][2 * k + 1] & 0x1FFFF;
                int idx = half ? ib : ia;
                uv[n][k] = xu[(size_t)idx * 32 + cl];
            }
#pragma unroll
        for (int n = 0; n < 4; ++n)
#pragma unroll
            for (int k = 0; k < 8; ++k) {
                float lo = b2f((unsigned short)(uv[n][k] & 0xFFFF));
                float hi = b2f((unsigned short)(uv[n][k] >> 16));
                if (k & 1) { B0[n] += lo; B1[n] += hi; }
                else       { A0[n] += lo; A1[n] += hi; }
            }
    }

    // ---- remainder chunks: wave-uniform scalar branches, issue-all then consume-all
    for (int c = 16; c < cmax; c += 16) {
        unsigned uc[4][8];
#pragma unroll
        for (int n = 0; n < 4; ++n)
            if (c < degp[n])
#pragma unroll
                for (int k = 0; k < 8; ++k) {
                    int ia = row[n][c + 2 * k] & 0x1FFFF;
                    int ib = row[n][c + 2 * k + 1] & 0x1FFFF;
                    int idx = half ? ib : ia;
                    uc[n][k] = xu[(size_t)idx * 32 + cl];
                }
#pragma unroll
        for (int n = 0; n < 4; ++n)
            if (c < degp[n])
#pragma unroll
                for (int k = 0; k < 8; ++k) {
                    float lo = b2f((unsigned short)(uc[n][k] & 0xFFFF));
                    float hi = b2f((unsigned short)(uc[n][k] >> 16));
                    if (k & 1) { B0[n] += lo; B1[n] += hi; }
                    else       { A0[n] += lo; A1[n] += hi; }
                }
    }

    // ---- reduce + BN affine + pack
#pragma unroll
    for (int n = 0; n < 4; ++n) {
        float S0 = (A0[n] + B0[n]);
        float S1 = (A1[n] + B1[n]);
        S0 += __shfl_xor(S0, 32);
        S1 += __shfl_xor(S1, 32);
        if (half == 0) {
            float selflo = b2f((unsigned short)(us[n] & 0xFFFF));
            float selfhi = b2f((unsigned short)(us[n] >> 16));
            float db = scale + (float)deg[n];
            float v0 = fmaf(a0f, fmaf(scale, selflo, S0), db * b0f);
            float v1 = fmaf(a1f, fmaf(scale, selfhi, S1), db * b1f);
            ((unsigned*)out)[(size_t)(nb + n) * 32 + cl] =
                (unsigned)f2b(v0) | ((unsigned)f2b(v1) << 16);
        }
    }
}

// ---------------- MFMA MLP v6: 64-row blocks, 1 M-tile/wave, zero barriers ----------------
// R10: mlp parallelism x2 (1563 blocks, ~24 waves/CU supply vs 12), pool loop halves
// to 16 iters. Each wave owns its 16 rows end-to-end (stage -> 3 mm stages -> ReLU ->
// writeback -> pool partials); xs rows are wave-private so no barrier until the
// cross-wave stats reduce. Stats atomics 8-way replicated.

__global__ __launch_bounds__(256, 4) void mlp_kernel(unsigned short* __restrict__ x,
                                                     const unsigned short* __restrict__ whi,
                                                     const unsigned short* __restrict__ wlo,
                                                     const float* __restrict__ bs, int l,
                                                     float* __restrict__ stats,
                                                     const int* __restrict__ graph_ids,
                                                     float* __restrict__ pooled, int last) {
    __shared__ __align__(16) unsigned short xs[64 * 64];   // 8 KB
    __shared__ int garr[64];
    __shared__ float ssum[256], sqq[256];
    int t = threadIdx.x;
    int nodebase = blockIdx.x * 64;
    int lane = t & 63, w = t >> 6;

    if (lane < 16) {
        int n = nodebase + w * 16 + lane;
        garr[w * 16 + lane] = (n < N_NODES) ? (graph_ids[n] & (N_GRAPHS - 1)) : -1;
    }
    // stage this wave's 16 rows (2 int4/lane; last block reads slack, rows masked later)
#pragma unroll
    for (int i = 0; i < 2; ++i) {
        int g = i * 64 + lane;
        int rl = g >> 3, qr = g & 7;
        int row = w * 16 + rl;
        const int4 v = *(const int4*)(x + (((size_t)(nodebase + row)) << 6) + qr * 8);
        *(int4*)&xs[XSH(row, qr)] = v;
    }
    // no barrier: xs rows and garr entries are wave-private until the stats reduce

    int m = lane & 15, q = lane >> 4;
    const float* bb = bs + l * 3 * 64;
    const unsigned short* whil = whi + (size_t)l * 12288;
    const unsigned short* wlol = wlo + (size_t)l * 12288;
    for (int mm = 0; mm < 3; ++mm) {
        // prefetch lo fragments (global loads go in flight now)
        short8 bl[2][4];
#pragma unroll
        for (int kc = 0; kc < 2; ++kc)
#pragma unroll
            for (int tj = 0; tj < 4; ++tj)
                bl[kc][tj] = *(const short8*)&wlol[(mm << 12) + XSH(tj * 16 + m, kc * 4 + q)];
        // A fragments (LDS, own rows)
        short8 a[2];
#pragma unroll
        for (int kc = 0; kc < 2; ++kc)
            a[kc] = *(const short8*)&xs[XSH(w * 16 + m, kc * 4 + q)];

        floatx4 acc[4];
#pragma unroll
        for (int tj = 0; tj < 4; ++tj) {
            float bv = bb[mm * 64 + tj * 16 + m];
            acc[tj] = (floatx4){bv, bv, bv, bv};
        }
        // hi chain (weights straight from global, L1/L2-hot)
#pragma unroll
        for (int kc = 0; kc < 2; ++kc) {
            short8 bh[4];
#pragma unroll
            for (int tj = 0; tj < 4; ++tj)
                bh[tj] = *(const short8*)&whil[(mm << 12) + XSH(tj * 16 + m, kc * 4 + q)];
#pragma unroll
            for (int tj = 0; tj < 4; ++tj)
                acc[tj] = __builtin_amdgcn_mfma_f32_16x16x32_bf16(a[kc], bh[tj], acc[tj], 0, 0, 0);
        }
        // lo chain (same accumulator)
#pragma unroll
        for (int kc = 0; kc < 2; ++kc)
#pragma unroll
            for (int tj = 0; tj < 4; ++tj)
                acc[tj] = __builtin_amdgcn_mfma_f32_16x16x32_bf16(a[kc], bl[kc][tj], acc[tj], 0, 0, 0);
        // ReLU + write-back (wave-local rows)
#pragma unroll
        for (int tj = 0; tj < 4; ++tj) {
            int col = tj * 16 + m;
#pragma unroll
            for (int r = 0; r < 4; ++r) {
                int row = w * 16 + q * 4 + r;
                float v = acc[tj][r];
                xs[XSH(row, col >> 3) + (col & 7)] = f2b(v > 0.f ? v : 0.f);
            }
        }
    }

    if (!last) {
        unsigned* xo = (unsigned*)x;
#pragma unroll
        for (int it = 0; it < 8; ++it) {
            int row = w * 16 + (lane >> 5) + it * 2;
            int cp = lane & 31;
            int col = cp * 2;
            unsigned val = *(const unsigned*)&xs[XSH(row, col >> 3) + (col & 7)];
            int node = nodebase + row;
            if (node < N_NODES) xo[(size_t)node * 32 + cp] = val;
        }
    }
    {
        int c = lane;
        float s = 0.f, q2 = 0.f, acc2 = 0.f;
        int cur = -1;
#pragma unroll
        for (int k = 0; k < 16; ++k) {
            int row = w * 16 + k;
            int g = garr[row];
            if (g >= 0) {
                float v = b2f(xs[XSH(row, c >> 3) + (c & 7)]);
                s += v;
                q2 += v * v;
                if (g != cur) {
                    if (cur >= 0) atomicAdd(&pooled[cur * 192 + l * 64 + c], acc2);
                    acc2 = 0.f;
                    cur = g;
                }
                acc2 += v;
            }
        }
        if (cur >= 0) atomicAdd(&pooled[cur * 192 + l * 64 + c], acc2);
        ssum[t] = s;
        sqq[t] = q2;
    }
    __syncthreads();
    if (t < 64) {
        float S = ssum[t] + ssum[t + 64] + ssum[t + 128] + ssum[t + 192];
        float Q = sqq[t] + sqq[t + 64] + sqq[t + 128] + sqq[t + 192];
        float* sp = stats + (blockIdx.x & (SREP - 1)) * SSTRIDE + l * 128;
        atomicAdd(&sp[t], S);
        atomicAdd(&sp[64 + t], Q);
    }
}

// ---------------- final classifier (replica-summed stats) ----------------

__global__ __launch_bounds__(256) void out_kernel(const float* __restrict__ pooled,
                                                  const float* __restrict__ stats,
                                                  const float* __restrict__ gamma,
                                                  const float* __restrict__ beta,
                                                  const int* __restrict__ gs,
                                                  const int* __restrict__ ge,
                                                  const float* __restrict__ Wo,
                                                  const float* __restrict__ bo,
                                                  float* __restrict__ out) {
    __shared__ float sab[384];
    int t = threadIdx.x;
    if (t < 192) {
        int l2 = t / 64, c = t & 63;
        float S = 0.f, Q = 0.f;
#pragma unroll
        for (int rp = 0; rp < SREP; ++rp) {
            S += stats[rp * SSTRIDE + l2 * 128 + c];
            Q += stats[rp * SSTRIDE + l2 * 128 + 64 + c];
        }
        float mean = S * (1.0f / N_NODES);
        float var = Q * (1.0f / N_NODES) - mean * mean;
        float rstd = rsqrtf(var + BN_EPS);
        float a = gamma[l2 * 64 + c] * rstd;
        sab[l2 * 128 + c] = a;
        sab[l2 * 128 + 64 + c] = beta[l2 * 64 + c] - mean * a;
    }
    __syncthreads();
    int idx = blockIdx.x * blockDim.x + t;
    if (idx < N_GRAPHS * NUM_CLASSES) {
        int g = idx / NUM_CLASSES, k = idx % NUM_CLASSES;
        float cg = (float)(ge[g] - gs[g]);
        float acc = bo[k];
        for (int l2 = 0; l2 < 3; ++l2)
            for (int c = 0; c < 64; ++c) {
                float gf = fmaf(sab[l2 * 128 + c], pooled[g * 192 + l2 * 64 + c],
                                sab[l2 * 128 + 64 + c] * cg);
                acc = fmaf(gf, Wo[(l2 * 64 + c) * NUM_CLASSES + k], acc);
            }
        out[idx] = acc;
    }
}

extern "C" void kernel_launch(void* const* d_in, const int* in_sizes, int n_in,
                              void* d_out, int out_size, void* d_ws, size_t ws_size,
                              hipStream_t stream) {
    const int*   node_ids  = (const int*)d_in[0];
    const int*   edge_src  = (const int*)d_in[1];
    const int*   edge_dst  = (const int*)d_in[2];
    const int*   graph_ids = (const int*)d_in[3];
    const float* emb       = (const float*)d_in[4];
    const float* Ws        = (const float*)d_in[5];
    const float* bs        = (const float*)d_in[6];
    const float* gamma     = (const float*)d_in[7];
    const float* beta      = (const float*)d_in[8];
    const float* eps       = (const float*)d_in[9];
    const float* W_out     = (const float*)d_in[10];
    const float* b_out     = (const float*)d_in[11];
    float* out = (float*)d_out;

    // workspace
    unsigned short* h    = (unsigned short*)d_ws;         // 6,400,000 sh (+8192 slack)
    unsigned short* xin  = h + 6400000 + 8192;            // 6,400,000 sh (+8192 slack)
    unsigned short* whi  = xin + 6400000 + 8192;          // 36,864 sh
    unsigned short* wlo  = whi + 36864;                   // 36,864 sh
    int*   srcs   = (int*)(wlo + 36864);                  // 6,400,000 i (padded CSR)
    int*   rec    = srcs + 6400000;                       // NUSED*BCAP i
    float* pooled = (float*)(rec + NUSED * BCAP);         // 98,304 f
    float* stats  = pooled + 98304;                       // SREP*SSTRIDE = 3,072 f
    int*   cnt    = (int*)(stats + SREP * SSTRIDE);       // 100,000 i
    int*   gs     = cnt + 100000;                         // 512 i
    int*   ge     = gs + 512;                             // 512 i
    int*   cursor = ge + 512;                             // 256 i (bucket totals)

    hipMemsetAsync(pooled, 0,
                   (size_t)(98304 + SREP * SSTRIDE + 100000 + 512 + 512 + 256) * 4, stream);

    prep_kernel<<<CBLK + WPBLK + EMBBLK, 1024, 0, stream>>>(
        edge_src, edge_dst, cursor, rec, Ws, whi, wlo,
        node_ids, graph_ids, emb, h, xin, gs, ge);
    fill_kernel<<<NUSED, 1024, 0, stream>>>(rec, cursor, cnt, srcs);

    const int MLP_BLK = (N_NODES + 63) / 64;   // 1563
    const int AGG_BLK = N_NODES / 16;          // 6250 blocks * 4 waves * 4 nodes
    for (int l = 0; l < 3; ++l) {
        unsigned short* X = (l % 2 == 0) ? h : xin;
        unsigned short* A = (l % 2 == 0) ? xin : h;
        agg_kernel<<<AGG_BLK, 256, 0, stream>>>(X, cnt, srcs, eps, l, stats, gamma, beta, A);
        mlp_kernel<<<MLP_BLK, 256, 0, stream>>>(A, whi, wlo, bs, l, stats, graph_ids, pooled, l == 2);
    }

    out_kernel<<<(N_GRAPHS * NUM_CLASSES + 255) / 256, 256, 0, stream>>>(
        pooled, stats, gamma, beta, gs, ge, W_out, b_out, out);
}

// Round 12
// 298.506 us; speedup vs baseline: 1.6726x; 1.0041x over previous
//
#include <hip/hip_runtime.h>

#define N_NODES 100000
#define N_EDGES 1600000
#define N_GRAPHS 512
#define HID 64
#define NUM_CLASSES 100
#define ID_OFFSET 1500
#define BN_EPS 1e-5f
#define CAP 64
#define NBKT 256
#define BSHIFT 9
#define NUSED ((N_NODES + 511) >> 9)   // 196 buckets of 512 nodes
#define BCAP 10240                      // per-bucket record capacity
#define CBLK 98
#define CHUNK 16384
#define WPBLK 5                         // wprep blocks inside prep_kernel
#define EMBBLK ((N_NODES * 32 + 1023) / 1024)   // 3125
#define ZWORDS (98304 + 3072 + 100000)  // pooled + stats + cnt (4B words)
#define ZBLK ((ZWORDS + 1023) / 1024)   // 197 zero blocks inside prep
#define DUMMY_ROW 100000                // zeroed row in x-buffer slack, pad target
#define SREP 8                          // stats atomic replicas
#define SSTRIDE 384                     // floats per stats replica

typedef __attribute__((ext_vector_type(8))) short short8;
typedef __attribute__((ext_vector_type(4))) float floatx4;

__device__ __forceinline__ float b2f(unsigned short u) {
    return __builtin_bit_cast(float, ((unsigned)u) << 16);
}
__device__ __forceinline__ unsigned short f2b(float f) {   // RNE
    unsigned x = __builtin_bit_cast(unsigned, f);
    x += 0x7FFFu + ((x >> 16) & 1u);
    return (unsigned short)(x >> 16);
}

// swizzled granule layout: 16-row tiles, 8 granules(16B)/row, granule slot = (row&15)^q
#define XSH(row, qq) ((((((row) >> 4) << 7) + ((qq) << 4) + (((row) & 15) ^ (qq))) * 8))

// ---------------- fused prep: binning + wprep + embed + workspace zero ----------------

__global__ __launch_bounds__(1024) void prep_kernel(const int* __restrict__ src,
                                                    const int* __restrict__ dst,
                                                    int* __restrict__ cursor,
                                                    int* __restrict__ rec,
                                                    const float* __restrict__ Ws,
                                                    unsigned short* __restrict__ whi,
                                                    unsigned short* __restrict__ wlo,
                                                    const int* __restrict__ node_ids,
                                                    const int* __restrict__ gid,
                                                    const float* __restrict__ emb,
                                                    unsigned short* __restrict__ h,
                                                    unsigned short* __restrict__ xin,
                                                    int* __restrict__ gs,
                                                    int* __restrict__ ge,
                                                    unsigned* __restrict__ zbase) {
    __shared__ int hist[NBKT];
    __shared__ int base_s[NBKT];
    int t = threadIdx.x;
    int blk = blockIdx.x;

    if (blk < CBLK) {
        // ---- dummy-row zeroing piggybacked on block 0 (replaces 2 memset launches)
        if (blk == 0 && t < 32) {
            ((unsigned*)(h + (size_t)DUMMY_ROW * 64))[t] = 0u;
            ((unsigned*)(xin + (size_t)DUMMY_ROW * 64))[t] = 0u;
        }
        // ---- edge binning (one pass) ----
        if (t < NBKT) hist[t] = 0;
        __syncthreads();
        int cb = blk * CHUNK;
        int d_[16], s_[16];
#pragma unroll
        for (int k = 0; k < 16; ++k) {
            int i = cb + k * 1024 + t;
            d_[k] = (i < N_EDGES) ? dst[i] : -1;
            s_[k] = (i < N_EDGES) ? src[i] : 0;
            if (d_[k] >= 0) atomicAdd(&hist[((unsigned)d_[k] >> BSHIFT) & (NBKT - 1)], 1);
        }
        __syncthreads();
        if (t < NBKT) base_s[t] = (hist[t] > 0) ? atomicAdd(&cursor[t], hist[t]) : 0;
        __syncthreads();
        if (t < NBKT) hist[t] = 0;
        __syncthreads();
#pragma unroll
        for (int k = 0; k < 16; ++k) {
            if (d_[k] >= 0) {
                unsigned d = (unsigned)d_[k];
                int b = (d >> BSHIFT) & (NBKT - 1);
                int p = atomicAdd(&hist[b], 1);
                int g = base_s[b] + p;
                if ((unsigned)g < BCAP)
                    rec[b * BCAP + g] = ((int)(d & 511) << 17) | (s_[k] & 0x1FFFF);
            }
        }
    } else if (blk < CBLK + WPBLK) {
        // ---- W pre-convert + pre-swizzle, hi/lo split ----
        int G = (blk - CBLK) * 1024 + t;
        if (G < 3 * 1536) {
            int l = G / 1536, Gp = G % 1536;
            int mm = Gp >> 9, rem = Gp & 511;
            int kq = rem >> 6, n = rem & 63;
            const float* Wp = Ws + l * 12288 + mm * 4096 + (kq * 8) * 64 + n;
            unsigned short uh[8], ul[8];
#pragma unroll
            for (int j = 0; j < 8; ++j) {
                float w = Wp[j * 64];
                unsigned short hi = f2b(w);
                uh[j] = hi;
                ul[j] = f2b(w - b2f(hi));
            }
            size_t off = (size_t)l * 12288 + (mm << 12) + XSH(n, kq);
            *(short8*)&whi[off] = *(short8*)uh;
            *(short8*)&wlo[off] = *(short8*)ul;
        }
    } else if (blk < CBLK + WPBLK + EMBBLK) {
        // ---- embedding gather (bf16) + sorted-graph span boundaries ----
        int idx = (blk - CBLK - WPBLK) * 1024 + t;
        if (idx < N_NODES * 32) {
            int n = idx >> 5, cp = idx & 31;
            const float2 e = *(const float2*)(emb + (((size_t)(node_ids[n] + ID_OFFSET)) << 6) + cp * 2);
            unsigned v = (unsigned)f2b(e.x) | ((unsigned)f2b(e.y) << 16);
            ((unsigned*)h)[n * 32 + cp] = v;
            if (cp == 0) {
                int g = gid[n] & (N_GRAPHS - 1);
                if (n == 0 || (gid[n - 1] & (N_GRAPHS - 1)) != g) gs[g] = n;
                if (n == N_NODES - 1 || (gid[n + 1] & (N_GRAPHS - 1)) != g) ge[g] = n + 1;
            }
        }
    } else {
        // ---- zero pooled + stats + cnt (consumers run in later kernels)
        int idx = (blk - CBLK - WPBLK - EMBBLK) * 1024 + t;
        if (idx < ZWORDS) zbase[idx] = 0u;
    }
}

// ---------------- per-bucket CSR fill (block-parallel pad to multiple of 16) ----------------

__global__ __launch_bounds__(1024) void fill_kernel(const int* __restrict__ rec,
                                                    const int* __restrict__ cursor,
                                                    int* __restrict__ cnt,
                                                    int* __restrict__ srcs) {
    __shared__ int lcnt[512];
    int t = threadIdx.x;
    int b = blockIdx.x;            // 0..NUSED-1
    if (t < 512) lcnt[t] = 0;
    __syncthreads();
    int nb = cursor[b];
    if (nb < 0) nb = 0;
    if (nb > BCAP) nb = BCAP;
    const int* seg = rec + b * BCAP;
    for (int i = t; i < nb; i += 1024) {
        unsigned r = (unsigned)seg[i];
        int dl = (int)((r >> 17) & 511);
        int s = (int)(r & 0x1FFFF);
        int node = (b << BSHIFT) + dl;
        int p = atomicAdd(&lcnt[dl], 1);
        if (p < CAP && node < N_NODES) srcs[(node << 6) + p] = s;
    }
    __syncthreads();
    if (t < 512) {
        int node = (b << BSHIFT) + t;
        if (node < N_NODES) cnt[node] = lcnt[t];
    }
    __syncthreads();
    // block-parallel padding: slot p of node nl gets DUMMY if degc <= p < degp
    for (int i = t; i < 512 * 64; i += 1024) {
        int nl = i >> 6, p = i & 63;
        int node = (b << BSHIFT) + nl;
        if (node < N_NODES) {
            int deg = lcnt[nl];
            int degc = deg > CAP ? CAP : deg;
            int degp = (degc + 15) & ~15;
            if (degp < 16) degp = 16;
            if (p >= degc && p < degp) srcs[(node << 6) + p] = DUMMY_ROW;
        }
    }
}

// ---------------- GIN aggregation (frozen: proven 2.15 TB/s; SREP-summed BN) ----------------

__global__ __launch_bounds__(256) void agg_kernel(const unsigned short* __restrict__ x,
                                                  const int* __restrict__ cnt,
                                                  const int* __restrict__ srcs,
                                                  const float* __restrict__ eps, int l,
                                                  const float* __restrict__ stats,
                                                  const float* __restrict__ gamma,
                                                  const float* __restrict__ beta,
                                                  unsigned short* __restrict__ out) {
    int nb = __builtin_amdgcn_readfirstlane(((blockIdx.x << 2) + (threadIdx.x >> 6)) << 2);
    int lane = threadIdx.x & 63;
    int half = lane >> 5;
    int cl = lane & 31;
    const unsigned* __restrict__ xu = (const unsigned*)x;

    // ---- BN coefficients for layer l-1 (replica-summed), prefetched early
    float scale = 1.0f + eps[l];
    float a0f = 1.0f, a1f = 1.0f, b0f = 0.0f, b1f = 0.0f;
    if (l > 0) {
        int lp = l - 1;
        float sm0 = 0.f, sm1 = 0.f, sq0 = 0.f, sq1 = 0.f;
#pragma unroll
        for (int rp = 0; rp < SREP; ++rp) {
            const float* sp = stats + rp * SSTRIDE + lp * 128;
            float2 a_ = *(const float2*)&sp[2 * cl];
            float2 b_ = *(const float2*)&sp[64 + 2 * cl];
            sm0 += a_.x; sm1 += a_.y;
            sq0 += b_.x; sq1 += b_.y;
        }
        float2 gm = *(const float2*)&gamma[lp * 64 + 2 * cl];
        float2 bt = *(const float2*)&beta[lp * 64 + 2 * cl];
        float mean0 = sm0 * (1.0f / N_NODES);
        float var0 = sq0 * (1.0f / N_NODES) - mean0 * mean0;
        float r0 = rsqrtf(var0 + BN_EPS);
        a0f = gm.x * r0;
        b0f = bt.x - mean0 * a0f;
        float mean1 = sm1 * (1.0f / N_NODES);
        float var1 = sq1 * (1.0f / N_NODES) - mean1 * mean1;
        float r1 = rsqrtf(var1 + BN_EPS);
        a1f = gm.y * r1;
        b1f = bt.y - mean1 * a1f;
    }

    // ---- degrees + row pointers for 4 consecutive nodes (scalar loads)
    int deg[4], degp[4];
    const int* row[4];
#pragma unroll
    for (int n = 0; n < 4; ++n) {
        int d = cnt[nb + n];
        int dc = d < 0 ? 0 : (d > CAP ? CAP : d);
        deg[n] = dc;
        int dp = (dc + 15) & ~15;
        degp[n] = dp < 16 ? 16 : dp;
        row[n] = srcs + ((size_t)(nb + n) << 6);
    }
    int cmax = degp[0];
    cmax = degp[1] > cmax ? degp[1] : cmax;
    cmax = degp[2] > cmax ? degp[2] : cmax;
    cmax = degp[3] > cmax ? degp[3] : cmax;

    // ---- self rows (issued alongside the gather burst)
    unsigned us[4];
#pragma unroll
    for (int n = 0; n < 4; ++n) us[n] = xu[(size_t)(nb + n) * 32 + cl];

    float A0[4] = {0.f, 0.f, 0.f, 0.f}, A1[4] = {0.f, 0.f, 0.f, 0.f};
    float B0[4] = {0.f, 0.f, 0.f, 0.f}, B1[4] = {0.f, 0.f, 0.f, 0.f};

    // ---- chunk 0: unconditional for all 4 nodes (rows padded to >=16), 32 loads in flight
    {
        unsigned uv[4][8];
#pragma unroll
        for (int n = 0; n < 4; ++n)
#pragma unroll
            for (int k = 0; k < 8; ++k) {
                int ia = row[n][2 * k] & 0x1FFFF;
                int ib = row[n][2 * k + 1] & 0x1FFFF;
                int idx = half ? ib : ia;
                uv[n][k] = xu[(size_t)idx * 32 + cl];
            }
#pragma unroll
        for (int n = 0; n < 4; ++n)
#pragma unroll
            for (int k = 0; k < 8; ++k) {
                float lo = b2f((unsigned short)(uv[n][k] & 0xFFFF));
                float hi = b2f((unsigned short)(uv[n][k] >> 16));
                if (k & 1) { B0[n] += lo; B1[n] += hi; }
                else       { A0[n] += lo; A1[n] += hi; }
            }
    }

    // ---- remainder chunks: wave-uniform scalar branches, issue-all then consume-all
    for (int c = 16; c < cmax; c += 16) {
        unsigned uc[4][8];
#pragma unroll
        for (int n = 0; n < 4; ++n)
            if (c < degp[n])
#pragma unroll
                for (int k = 0; k < 8; ++k) {
                    int ia = row[n][c + 2 * k] & 0x1FFFF;
                    int ib = row[n][c + 2 * k + 1] & 0x1FFFF;
                    int idx = half ? ib : ia;
                    uc[n][k] = xu[(size_t)idx * 32 + cl];
                }
#pragma unroll
        for (int n = 0; n < 4; ++n)
            if (c < degp[n])
#pragma unroll
                for (int k = 0; k < 8; ++k) {
                    float lo = b2f((unsigned short)(uc[n][k] & 0xFFFF));
                    float hi = b2f((unsigned short)(uc[n][k] >> 16));
                    if (k & 1) { B0[n] += lo; B1[n] += hi; }
                    else       { A0[n] += lo; A1[n] += hi; }
                }
    }

    // ---- reduce + BN affine + pack
#pragma unroll
    for (int n = 0; n < 4; ++n) {
        float S0 = (A0[n] + B0[n]);
        float S1 = (A1[n] + B1[n]);
        S0 += __shfl_xor(S0, 32);
        S1 += __shfl_xor(S1, 32);
        if (half == 0) {
            float selflo = b2f((unsigned short)(us[n] & 0xFFFF));
            float selfhi = b2f((unsigned short)(us[n] >> 16));
            float db = scale + (float)deg[n];
            float v0 = fmaf(a0f, fmaf(scale, selflo, S0), db * b0f);
            float v1 = fmaf(a1f, fmaf(scale, selfhi, S1), db * b1f);
            ((unsigned*)out)[(size_t)(nb + n) * 32 + cl] =
                (unsigned)f2b(v0) | ((unsigned)f2b(v1) << 16);
        }
    }
}

// ---------------- MFMA MLP v7: direct-global A for stage 0, no initial LDS staging ----------------
// R11: mm0's A fragment is loadable straight from row-major global x (lane(m,q) reads
// 16B at x[row=m][kc*32+q*8]) -> delete the global->reg->LDS-write->LDS-read chain head
// (~900 cyc serial). a0 loads are issued at kernel top, in flight with the bl/bh weight
// prefetches. xs is first written by mm0's C-writeback (wave-private rows, no barrier).

__global__ __launch_bounds__(256, 4) void mlp_kernel(unsigned short* __restrict__ x,
                                                     const unsigned short* __restrict__ whi,
                                                     const unsigned short* __restrict__ wlo,
                                                     const float* __restrict__ bs, int l,
                                                     float* __restrict__ stats,
                                                     const int* __restrict__ graph_ids,
                                                     float* __restrict__ pooled, int last) {
    __shared__ __align__(16) unsigned short xs[64 * 64];   // 8 KB
    __shared__ int garr[64];
    __shared__ float ssum[256], sqq[256];
    int t = threadIdx.x;
    int nodebase = blockIdx.x * 64;
    int lane = t & 63, w = t >> 6;
    int m = lane & 15, q = lane >> 4;

    // mm0 A fragments straight from global (issued first; slack rows masked later)
    const unsigned short* xrow = x + (((size_t)(nodebase + w * 16 + m)) << 6);
    short8 a0[2];
#pragma unroll
    for (int kc = 0; kc < 2; ++kc)
        a0[kc] = *(const short8*)&xrow[kc * 32 + q * 8];

    if (lane < 16) {
        int n = nodebase + w * 16 + lane;
        garr[w * 16 + lane] = (n < N_NODES) ? (graph_ids[n] & (N_GRAPHS - 1)) : -1;
    }
    // no barrier: xs rows and garr entries are wave-private until the stats reduce

    const float* bb = bs + l * 3 * 64;
    const unsigned short* whil = whi + (size_t)l * 12288;
    const unsigned short* wlol = wlo + (size_t)l * 12288;
    for (int mm = 0; mm < 3; ++mm) {
        // prefetch lo fragments (global loads go in flight now)
        short8 bl[2][4];
#pragma unroll
        for (int kc = 0; kc < 2; ++kc)
#pragma unroll
            for (int tj = 0; tj < 4; ++tj)
                bl[kc][tj] = *(const short8*)&wlol[(mm << 12) + XSH(tj * 16 + m, kc * 4 + q)];
        // A fragments: direct-global for mm0, LDS for later stages
        short8 a[2];
        if (mm == 0) {
#pragma unroll
            for (int kc = 0; kc < 2; ++kc) a[kc] = a0[kc];
        } else {
#pragma unroll
            for (int kc = 0; kc < 2; ++kc)
                a[kc] = *(const short8*)&xs[XSH(w * 16 + m, kc * 4 + q)];
        }

        floatx4 acc[4];
#pragma unroll
        for (int tj = 0; tj < 4; ++tj) {
            float bv = bb[mm * 64 + tj * 16 + m];
            acc[tj] = (floatx4){bv, bv, bv, bv};
        }
        // hi chain (weights straight from global, L1/L2-hot)
#pragma unroll
        for (int kc = 0; kc < 2; ++kc) {
            short8 bh[4];
#pragma unroll
            for (int tj = 0; tj < 4; ++tj)
                bh[tj] = *(const short8*)&whil[(mm << 12) + XSH(tj * 16 + m, kc * 4 + q)];
#pragma unroll
            for (int tj = 0; tj < 4; ++tj)
                acc[tj] = __builtin_amdgcn_mfma_f32_16x16x32_bf16(a[kc], bh[tj], acc[tj], 0, 0, 0);
        }
        // lo chain (same accumulator)
#pragma unroll
        for (int kc = 0; kc < 2; ++kc)
#pragma unroll
            for (int tj = 0; tj < 4; ++tj)
                acc[tj] = __builtin_amdgcn_mfma_f32_16x16x32_bf16(a[kc], bl[kc][tj], acc[tj], 0, 0, 0);
        // ReLU + write-back (wave-local rows)
#pragma unroll
        for (int tj = 0; tj < 4; ++tj) {
            int col = tj * 16 + m;
#pragma unroll
            for (int r = 0; r < 4; ++r) {
                int row = w * 16 + q * 4 + r;
                float v = acc[tj][r];
                xs[XSH(row, col >> 3) + (col & 7)] = f2b(v > 0.f ? v : 0.f);
            }
        }
    }

    if (!last) {
        unsigned* xo = (unsigned*)x;
#pragma unroll
        for (int it = 0; it < 8; ++it) {
            int row = w * 16 + (lane >> 5) + it * 2;
            int cp = lane & 31;
            int col = cp * 2;
            unsigned val = *(const unsigned*)&xs[XSH(row, col >> 3) + (col & 7)];
            int node = nodebase + row;
            if (node < N_NODES) xo[(size_t)node * 32 + cp] = val;
        }
    }
    {
        int c = lane;
        float s = 0.f, q2 = 0.f, acc2 = 0.f;
        int cur = -1;
#pragma unroll
        for (int k = 0; k < 16; ++k) {
            int row = w * 16 + k;
            int g = garr[row];
            if (g >= 0) {
                float v = b2f(xs[XSH(row, c >> 3) + (c & 7)]);
                s += v;
                q2 += v * v;
                if (g != cur) {
                    if (cur >= 0) atomicAdd(&pooled[cur * 192 + l * 64 + c], acc2);
                    acc2 = 0.f;
                    cur = g;
                }
                acc2 += v;
            }
        }
        if (cur >= 0) atomicAdd(&pooled[cur * 192 + l * 64 + c], acc2);
        ssum[t] = s;
        sqq[t] = q2;
    }
    __syncthreads();
    if (t < 64) {
        float S = ssum[t] + ssum[t + 64] + ssum[t + 128] + ssum[t + 192];
        float Q = sqq[t] + sqq[t + 64] + sqq[t + 128] + sqq[t + 192];
        float* sp = stats + (blockIdx.x & (SREP - 1)) * SSTRIDE + l * 128;
        atomicAdd(&sp[t], S);
        atomicAdd(&sp[64 + t], Q);
    }
}

// ---------------- final classifier (replica-summed stats) ----------------

__global__ __launch_bounds__(256) void out_kernel(const float* __restrict__ pooled,
                                                  const float* __restrict__ stats,
                                                  const float* __restrict__ gamma,
                                                  const float* __restrict__ beta,
                                                  const int* __restrict__ gs,
                                                  const int* __restrict__ ge,
                                                  const float* __restrict__ Wo,
                                                  const float* __restrict__ bo,
                                                  float* __restrict__ out) {
    __shared__ float sab[384];
    int t = threadIdx.x;
    if (t < 192) {
        int l2 = t / 64, c = t & 63;
        float S = 0.f, Q = 0.f;
#pragma unroll
        for (int rp = 0; rp < SREP; ++rp) {
            S += stats[rp * SSTRIDE + l2 * 128 + c];
            Q += stats[rp * SSTRIDE + l2 * 128 + 64 + c];
        }
        float mean = S * (1.0f / N_NODES);
        float var = Q * (1.0f / N_NODES) - mean * mean;
        float rstd = rsqrtf(var + BN_EPS);
        float a = gamma[l2 * 64 + c] * rstd;
        sab[l2 * 128 + c] = a;
        sab[l2 * 128 + 64 + c] = beta[l2 * 64 + c] - mean * a;
    }
    __syncthreads();
    int idx = blockIdx.x * blockDim.x + t;
    if (idx < N_GRAPHS * NUM_CLASSES) {
        int g = idx / NUM_CLASSES, k = idx % NUM_CLASSES;
        float cg = (float)(ge[g] - gs[g]);
        float acc = bo[k];
        for (int l2 = 0; l2 < 3; ++l2)
            for (int c = 0; c < 64; ++c) {
                float gf = fmaf(sab[l2 * 128 + c], pooled[g * 192 + l2 * 64 + c],
                                sab[l2 * 128 + 64 + c] * cg);
                acc = fmaf(gf, Wo[(l2 * 64 + c) * NUM_CLASSES + k], acc);
            }
        out[idx] = acc;
    }
}

extern "C" void kernel_launch(void* const* d_in, const int* in_sizes, int n_in,
                              void* d_out, int out_size, void* d_ws, size_t ws_size,
                              hipStream_t stream) {
    const int*   node_ids  = (const int*)d_in[0];
    const int*   edge_src  = (const int*)d_in[1];
    const int*   edge_dst  = (const int*)d_in[2];
    const int*   graph_ids = (const int*)d_in[3];
    const float* emb       = (const float*)d_in[4];
    const float* Ws        = (const float*)d_in[5];
    const float* bs        = (const float*)d_in[6];
    const float* gamma     = (const float*)d_in[7];
    const float* beta      = (const float*)d_in[8];
    const float* eps       = (const float*)d_in[9];
    const float* W_out     = (const float*)d_in[10];
    const float* b_out     = (const float*)d_in[11];
    float* out = (float*)d_out;

    // workspace
    unsigned short* h    = (unsigned short*)d_ws;         // 6,400,000 sh (+8192 slack)
    unsigned short* xin  = h + 6400000 + 8192;            // 6,400,000 sh (+8192 slack)
    unsigned short* whi  = xin + 6400000 + 8192;          // 36,864 sh
    unsigned short* wlo  = whi + 36864;                   // 36,864 sh
    int*   srcs   = (int*)(wlo + 36864);                  // 6,400,000 i (padded CSR)
    int*   rec    = srcs + 6400000;                       // NUSED*BCAP i
    float* pooled = (float*)(rec + NUSED * BCAP);         // 98,304 f
    float* stats  = pooled + 98304;                       // SREP*SSTRIDE = 3,072 f
    int*   cnt    = (int*)(stats + SREP * SSTRIDE);       // 100,000 i
    int*   gs     = cnt + 100000;                         // 512 i
    int*   ge     = gs + 512;                             // 512 i
    int*   cursor = ge + 512;                             // 256 i (bucket totals)

    // only gs/ge/cursor need host-side zero (gs/ge race with prep's own writers;
    // cursor is prep's atomic basis). pooled/stats/cnt zeroed inside prep.
    hipMemsetAsync(gs, 0, (size_t)(512 + 512 + 256) * 4, stream);

    prep_kernel<<<CBLK + WPBLK + EMBBLK + ZBLK, 1024, 0, stream>>>(
        edge_src, edge_dst, cursor, rec, Ws, whi, wlo,
        node_ids, graph_ids, emb, h, xin, gs, ge, (unsigned*)pooled);
    fill_kernel<<<NUSED, 1024, 0, stream>>>(rec, cursor, cnt, srcs);

    const int MLP_BLK = (N_NODES + 63) / 64;   // 1563
    const int AGG_BLK = N_NODES / 16;          // 6250 blocks * 4 waves * 4 nodes
    for (int l = 0; l < 3; ++l) {
        unsigned short* X = (l % 2 == 0) ? h : xin;
        unsigned short* A = (l % 2 == 0) ? xin : h;
        agg_kernel<<<AGG_BLK, 256, 0, stream>>>(X, cnt, srcs, eps, l, stats, gamma, beta, A);
        mlp_kernel<<<MLP_BLK, 256, 0, stream>>>(A, whi, wlo, bs, l, stats, graph_ids, pooled, l == 2);
    }

    out_kernel<<<(N_GRAPHS * NUM_CLASSES + 255) / 256, 256, 0, stream>>>(
        pooled, stats, gamma, beta, gs, ge, W_out, b_out, out);
}